// Round 8
// baseline (55.015 us; speedup 1.0000x reference)
//
#include <hip/hip_runtime.h>
#include <cstdint>
#include <cstddef>

#define B_ 8
#define N_ 2048
#define M_ 256
#define KD 64
#define DD 128
#define BN (B_ * N_)
#define KSPLIT 4
#define KT_PER (N_ / 64 / KSPLIT)   // 8 key-tiles of 64 per block

typedef __attribute__((ext_vector_type(8))) short s16x8;
typedef __attribute__((ext_vector_type(4))) float f32x4;
typedef __attribute__((ext_vector_type(4))) unsigned int u32x4;

__device__ __forceinline__ float elu_f(float x) {
    return x > 0.f ? x : (__expf(x) - 1.f);
}

// f32 -> bf16 round-to-nearest-even, raw bits
__device__ __forceinline__ unsigned short f2bf(float f) {
    unsigned int u = __float_as_uint(f);
    u = (u + 0x7FFFu + ((u >> 16) & 1u)) >> 16;
    return (unsigned short)u;
}
__device__ __forceinline__ float bf2f(unsigned short h) {
    return __uint_as_float((unsigned int)h << 16);
}
__device__ __forceinline__ unsigned short bflo(float f, unsigned short h) {
    return f2bf(f - bf2f(h));
}
// one float -> packed (hi | lo<<16) word
__device__ __forceinline__ unsigned int packw(float f) {
    unsigned short h = f2bf(f);
    unsigned short lo = bflo(f, h);
    return (unsigned int)h | ((unsigned int)lo << 16);
}
__device__ __forceinline__ unsigned int bfpack2(float a, float b) {
    return (unsigned int)f2bf(a) | ((unsigned int)f2bf(b) << 16);
}

// unpack 8 packed (hi|lo<<16) words -> hi-frag and lo-frag
__device__ __forceinline__ void unpack8(const unsigned int* ip, s16x8& ahi, s16x8& alo) {
    const uint4 u0 = *reinterpret_cast<const uint4*>(ip);
    const uint4 u1 = *reinterpret_cast<const uint4*>(ip + 4);
    u32x4 hv, lv;
    hv.x = __byte_perm(u0.x, u0.y, 0x5410);
    hv.y = __byte_perm(u0.z, u0.w, 0x5410);
    hv.z = __byte_perm(u1.x, u1.y, 0x5410);
    hv.w = __byte_perm(u1.z, u1.w, 0x5410);
    lv.x = __byte_perm(u0.x, u0.y, 0x7632);
    lv.y = __byte_perm(u0.z, u0.w, 0x7632);
    lv.z = __byte_perm(u1.x, u1.y, 0x7632);
    lv.w = __byte_perm(u1.z, u1.w, 0x7632);
    ahi = __builtin_bit_cast(s16x8, hv);
    alo = __builtin_bit_cast(s16x8, lv);
}

// ---------------------------------------------------------------------------
// One-time weight pack (layout unchanged):
//   qkv:  base = (((mat*4+ct)*8+c)*64+lane)*8        (K=256: 8 chunks, 4 ct)
//   W1:   base = ((ct*2+c)*64+lane)*8                (K=64:  2 chunks, 8 ct)
//   W2/3: base = ((ct*4+c)*64+lane)*8                (K=128: 4 chunks, 8 ct)
// Element at (k = c*32+(lane>>4)*8+j, col = ct*16+(lane&15)).
// ---------------------------------------------------------------------------
__global__ __launch_bounds__(256)
void pack_kernel(const float* __restrict__ Wq, const float* __restrict__ Wk,
                 const float* __restrict__ Wv, const float* __restrict__ W1,
                 const float* __restrict__ W2, const float* __restrict__ W3,
                 unsigned short* __restrict__ pQh, unsigned short* __restrict__ pQl,
                 unsigned short* __restrict__ pW1h, unsigned short* __restrict__ pW1l,
                 unsigned short* __restrict__ pW2h, unsigned short* __restrict__ pW2l,
                 unsigned short* __restrict__ pW3h, unsigned short* __restrict__ pW3l) {
    const int id = blockIdx.x * 256 + threadIdx.x;   // 0..11263
    const float* W;
    unsigned short *ph, *pl;
    int ncol, ct, c, lane, base;
    if (id < 6144) {
        int mat = id >> 11, rem = id & 2047;
        ct = rem >> 9; c = (rem >> 6) & 7; lane = rem & 63;
        W = (mat == 0) ? Wq : (mat == 1) ? Wk : Wv;
        ncol = KD; ph = pQh; pl = pQl;
        base = (((mat * 4 + ct) * 8 + c) * 64 + lane) * 8;
    } else {
        int id2 = id - 6144;
        if (id2 < 1024) {
            ct = id2 >> 7; c = (id2 >> 6) & 1; lane = id2 & 63;
            W = W1; ncol = DD; ph = pW1h; pl = pW1l;
            base = ((ct * 2 + c) * 64 + lane) * 8;
        } else if (id2 < 3072) {
            int id3 = id2 - 1024;
            ct = id3 >> 8; c = (id3 >> 6) & 3; lane = id3 & 63;
            W = W2; ncol = DD; ph = pW2h; pl = pW2l;
            base = ((ct * 4 + c) * 64 + lane) * 8;
        } else {
            int id3 = id2 - 3072;
            ct = id3 >> 8; c = (id3 >> 6) & 3; lane = id3 & 63;
            W = W3; ncol = DD; ph = pW3h; pl = pW3l;
            base = ((ct * 4 + c) * 64 + lane) * 8;
        }
    }
    const int col = ct * 16 + (lane & 15);
    const int kb = c * 32 + (lane >> 4) * 8;
    #pragma unroll
    for (int j = 0; j < 8; ++j) {
        float v = W[(size_t)(kb + j) * ncol + col];
        unsigned short h = f2bf(v);
        ph[base + j] = h;
        pl[base + j] = bflo(v, h);
    }
}

// ---------------------------------------------------------------------------
// QKV projection, single-bf16 MFMA. 512 blocks x 32 rows, 256 thr (4 waves).
// Wave w owns 3 (mat,ct) tiles for BOTH 16-row strips (B-frags reused -> half
// the weight L2 traffic of the 16-row version).
// ---------------------------------------------------------------------------
__global__ __launch_bounds__(256)
void qkv_kernel(const float* __restrict__ x,
                const unsigned short* __restrict__ pQh,
                unsigned short* __restrict__ qb, unsigned short* __restrict__ kb,
                unsigned short* __restrict__ vtb) {
    __shared__ unsigned short xh[32 * 264];
    __shared__ float dbuf[32 * 204];
    const int t = threadIdx.x;
    const int row0 = blockIdx.x * 32;

    for (int i = t; i < 2048; i += 256) {       // 32 rows x 64 float4
        int rr = i >> 6, c4 = i & 63;
        float4 v = reinterpret_cast<const float4*>(x + (size_t)(row0 + rr) * M_)[c4];
        ushort4 o;
        o.x = f2bf(v.x); o.y = f2bf(v.y); o.z = f2bf(v.z); o.w = f2bf(v.w);
        *reinterpret_cast<ushort4*>(&xh[rr * 264 + c4 * 4]) = o;
    }
    __syncthreads();

    const int w = t >> 6, l = t & 63, g = l >> 4, r = l & 15;
    const int t0 = 3 * w, t1 = 3 * w + 1, t2 = 3 * w + 2;

    f32x4 acc[3][2];
    #pragma unroll
    for (int m = 0; m < 3; ++m)
        #pragma unroll
        for (int s = 0; s < 2; ++s)
            acc[m][s] = (f32x4){0.f, 0.f, 0.f, 0.f};

    #pragma unroll
    for (int c = 0; c < 8; ++c) {
        const s16x8 a0 = *reinterpret_cast<const s16x8*>(&xh[r * 264 + c * 32 + g * 8]);
        const s16x8 a1 = *reinterpret_cast<const s16x8*>(&xh[(16 + r) * 264 + c * 32 + g * 8]);
        const s16x8 b0 = *reinterpret_cast<const s16x8*>(pQh + ((t0 * 8 + c) * 64 + l) * 8);
        const s16x8 b1 = *reinterpret_cast<const s16x8*>(pQh + ((t1 * 8 + c) * 64 + l) * 8);
        const s16x8 b2 = *reinterpret_cast<const s16x8*>(pQh + ((t2 * 8 + c) * 64 + l) * 8);
        acc[0][0] = __builtin_amdgcn_mfma_f32_16x16x32_bf16(a0, b0, acc[0][0], 0, 0, 0);
        acc[0][1] = __builtin_amdgcn_mfma_f32_16x16x32_bf16(a1, b0, acc[0][1], 0, 0, 0);
        acc[1][0] = __builtin_amdgcn_mfma_f32_16x16x32_bf16(a0, b1, acc[1][0], 0, 0, 0);
        acc[1][1] = __builtin_amdgcn_mfma_f32_16x16x32_bf16(a1, b1, acc[1][1], 0, 0, 0);
        acc[2][0] = __builtin_amdgcn_mfma_f32_16x16x32_bf16(a0, b2, acc[2][0], 0, 0, 0);
        acc[2][1] = __builtin_amdgcn_mfma_f32_16x16x32_bf16(a1, b2, acc[2][1], 0, 0, 0);
    }

    // D-frags -> dbuf: col = mat*68 + ct*16 + r, row = s*16 + 4g+reg
    {
        const int c0 = (t0 >> 2) * 68 + (t0 & 3) * 16 + r;
        const int c1 = (t1 >> 2) * 68 + (t1 & 3) * 16 + r;
        const int c2 = (t2 >> 2) * 68 + (t2 & 3) * 16 + r;
        #pragma unroll
        for (int s = 0; s < 2; ++s)
            #pragma unroll
            for (int reg = 0; reg < 4; ++reg) {
                const int rw = (s * 16 + 4 * g + reg) * 204;
                dbuf[rw + c0] = acc[0][s][reg];
                dbuf[rw + c1] = acc[1][s][reg];
                dbuf[rw + c2] = acc[2][s][reg];
            }
    }
    __syncthreads();

    const int b = row0 >> 11, n0 = row0 & 2047;
    {
        // q (mat 0, scaled 0.125) / k (mat 1): 2 mats x 32 rows x 4 quarters
        const int mat = t >> 7, rem = t & 127, rr = rem >> 2, cq = rem & 3;
        const float* src = &dbuf[rr * 204 + mat * 68 + cq * 16];
        float4 v0 = *reinterpret_cast<const float4*>(src);
        float4 v1 = *reinterpret_cast<const float4*>(src + 4);
        float4 v2 = *reinterpret_cast<const float4*>(src + 8);
        float4 v3 = *reinterpret_cast<const float4*>(src + 12);
        const float sc = (mat == 0) ? 0.125f : 1.0f;
        uint4 o0, o1;
        o0.x = bfpack2(v0.x * sc, v0.y * sc);
        o0.y = bfpack2(v0.z * sc, v0.w * sc);
        o0.z = bfpack2(v1.x * sc, v1.y * sc);
        o0.w = bfpack2(v1.z * sc, v1.w * sc);
        o1.x = bfpack2(v2.x * sc, v2.y * sc);
        o1.y = bfpack2(v2.z * sc, v2.w * sc);
        o1.z = bfpack2(v3.x * sc, v3.y * sc);
        o1.w = bfpack2(v3.z * sc, v3.w * sc);
        unsigned short* dst = (mat == 0 ? qb : kb) + (size_t)(row0 + rr) * KD + cq * 16;
        *reinterpret_cast<uint4*>(dst)     = o0;
        *reinterpret_cast<uint4*>(dst + 8) = o1;
    }
    {
        // v transposed: 64 d x 32 n -> thread: d = t>>2, 8 n
        const int d = t >> 2, ng = (t & 3) * 8;
        unsigned short tmp[8];
        #pragma unroll
        for (int i = 0; i < 8; ++i)
            tmp[i] = f2bf(dbuf[(ng + i) * 204 + 136 + d]);
        uint4 o0;
        o0.x = (unsigned)tmp[0] | ((unsigned)tmp[1] << 16);
        o0.y = (unsigned)tmp[2] | ((unsigned)tmp[3] << 16);
        o0.z = (unsigned)tmp[4] | ((unsigned)tmp[5] << 16);
        o0.w = (unsigned)tmp[6] | ((unsigned)tmp[7] << 16);
        *reinterpret_cast<uint4*>(vtb + ((size_t)b * KD + d) * N_ + n0 + ng) = o0;
    }
}

// ---------------------------------------------------------------------------
// MFMA flash attention, split-K. 1024 blocks x 128 thr: 2 waves x 32 q-rows.
// Each wave reads the K/V LDS tiles ONCE for 32 rows (half the LDS traffic
// per q-row vs 16-row waves). LDS-staged K/V with register prefetch, no-max
// softmax, deferred l-butterfly, wave-local P fence.
// ---------------------------------------------------------------------------
__global__ __launch_bounds__(128)
void attn_kernel(const unsigned short* __restrict__ qb,
                 const unsigned short* __restrict__ kb,
                 const unsigned short* __restrict__ vtb,
                 float* __restrict__ Zp, float* __restrict__ lsum) {
    __shared__ __align__(16) unsigned short ks[64 * 72];
    __shared__ __align__(16) unsigned short vt[64 * 72];
    __shared__ __align__(16) unsigned short ps[2 * 32 * 72];

    const int t = threadIdx.x;
    const int w = t >> 6;
    const int l = t & 63;
    const int g = l >> 4;
    const int r = l & 15;
    const int bid = blockIdx.x;
    const int split = bid & 3;
    const int qt = (bid >> 2) & 31;      // 64-row q tile
    const int bb = bid >> 7;
    const int qrow0 = qt * 64 + w * 32;  // this wave's 32 rows
    const int k0 = split * (N_ / KSPLIT);

    // Q A-frags for both 16-row strips
    const unsigned short* qrowA = qb + ((size_t)bb * N_ + qrow0 + r) * KD + g * 8;
    const unsigned short* qrowB = qrowA + (size_t)16 * KD;
    const s16x8 qfA0 = *reinterpret_cast<const s16x8*>(qrowA);
    const s16x8 qfA1 = *reinterpret_cast<const s16x8*>(qrowA + 32);
    const s16x8 qfB0 = *reinterpret_cast<const s16x8*>(qrowB);
    const s16x8 qfB1 = *reinterpret_cast<const s16x8*>(qrowB + 32);

    const unsigned short* kbase = kb + ((size_t)bb * N_ + k0) * KD;
    const unsigned short* vbase = vtb + (size_t)bb * KD * N_ + k0;
    unsigned short* psw = ps + w * (32 * 72);

    // prologue: stage tile 0 (128 thr: 4 chunks each of K and V)
    for (int c = t; c < 512; c += 128) {
        int key = c >> 3, sub = c & 7;
        *reinterpret_cast<s16x8*>(&ks[key * 72 + sub * 8]) =
            *reinterpret_cast<const s16x8*>(kbase + (size_t)key * KD + sub * 8);
        *reinterpret_cast<s16x8*>(&vt[key * 72 + sub * 8]) =
            *reinterpret_cast<const s16x8*>(vbase + (size_t)key * N_ + sub * 8);
    }
    __syncthreads();

    f32x4 zacA0 = {0.f,0.f,0.f,0.f}, zacA1 = {0.f,0.f,0.f,0.f};
    f32x4 zacA2 = {0.f,0.f,0.f,0.f}, zacA3 = {0.f,0.f,0.f,0.f};
    f32x4 zacB0 = {0.f,0.f,0.f,0.f}, zacB1 = {0.f,0.f,0.f,0.f};
    f32x4 zacB2 = {0.f,0.f,0.f,0.f}, zacB3 = {0.f,0.f,0.f,0.f};
    float laccA[4] = {0.f, 0.f, 0.f, 0.f};
    float laccB[4] = {0.f, 0.f, 0.f, 0.f};

    for (int kt = 0; kt < KT_PER; ++kt) {
        // ---- prefetch next tile into regs ----
        s16x8 kr[4], vr[4];
        const bool pf = (kt + 1 < KT_PER);
        if (pf) {
            const unsigned short* kg = kbase + (size_t)(kt + 1) * 64 * KD;
            const unsigned short* vg = vbase + (size_t)(kt + 1) * 64;
            #pragma unroll
            for (int i = 0; i < 4; ++i) {
                const int c = t + 128 * i, key = c >> 3, sub = c & 7;
                kr[i] = *reinterpret_cast<const s16x8*>(kg + (size_t)key * KD + sub * 8);
                vr[i] = *reinterpret_cast<const s16x8*>(vg + (size_t)key * N_ + sub * 8);
            }
        }

        // ---- QK^T: 8 shared K-frag reads, 16 MFMA (2 strips) ----
        f32x4 sA0 = {0.f,0.f,0.f,0.f}, sA1 = {0.f,0.f,0.f,0.f};
        f32x4 sA2 = {0.f,0.f,0.f,0.f}, sA3 = {0.f,0.f,0.f,0.f};
        f32x4 sB0 = {0.f,0.f,0.f,0.f}, sB1 = {0.f,0.f,0.f,0.f};
        f32x4 sB2 = {0.f,0.f,0.f,0.f}, sB3 = {0.f,0.f,0.f,0.f};
        {
            const s16x8 kf00 = *reinterpret_cast<const s16x8*>(&ks[(r +  0) * 72 + g * 8]);
            const s16x8 kf01 = *reinterpret_cast<const s16x8*>(&ks[(r +  0) * 72 + g * 8 + 32]);
            const s16x8 kf10 = *reinterpret_cast<const s16x8*>(&ks[(r + 16) * 72 + g * 8]);
            const s16x8 kf11 = *reinterpret_cast<const s16x8*>(&ks[(r + 16) * 72 + g * 8 + 32]);
            const s16x8 kf20 = *reinterpret_cast<const s16x8*>(&ks[(r + 32) * 72 + g * 8]);
            const s16x8 kf21 = *reinterpret_cast<const s16x8*>(&ks[(r + 32) * 72 + g * 8 + 32]);
            const s16x8 kf30 = *reinterpret_cast<const s16x8*>(&ks[(r + 48) * 72 + g * 8]);
            const s16x8 kf31 = *reinterpret_cast<const s16x8*>(&ks[(r + 48) * 72 + g * 8 + 32]);
            sA0 = __builtin_amdgcn_mfma_f32_16x16x32_bf16(qfA0, kf00, sA0, 0, 0, 0);
            sA0 = __builtin_amdgcn_mfma_f32_16x16x32_bf16(qfA1, kf01, sA0, 0, 0, 0);
            sA1 = __builtin_amdgcn_mfma_f32_16x16x32_bf16(qfA0, kf10, sA1, 0, 0, 0);
            sA1 = __builtin_amdgcn_mfma_f32_16x16x32_bf16(qfA1, kf11, sA1, 0, 0, 0);
            sA2 = __builtin_amdgcn_mfma_f32_16x16x32_bf16(qfA0, kf20, sA2, 0, 0, 0);
            sA2 = __builtin_amdgcn_mfma_f32_16x16x32_bf16(qfA1, kf21, sA2, 0, 0, 0);
            sA3 = __builtin_amdgcn_mfma_f32_16x16x32_bf16(qfA0, kf30, sA3, 0, 0, 0);
            sA3 = __builtin_amdgcn_mfma_f32_16x16x32_bf16(qfA1, kf31, sA3, 0, 0, 0);
            sB0 = __builtin_amdgcn_mfma_f32_16x16x32_bf16(qfB0, kf00, sB0, 0, 0, 0);
            sB0 = __builtin_amdgcn_mfma_f32_16x16x32_bf16(qfB1, kf01, sB0, 0, 0, 0);
            sB1 = __builtin_amdgcn_mfma_f32_16x16x32_bf16(qfB0, kf10, sB1, 0, 0, 0);
            sB1 = __builtin_amdgcn_mfma_f32_16x16x32_bf16(qfB1, kf11, sB1, 0, 0, 0);
            sB2 = __builtin_amdgcn_mfma_f32_16x16x32_bf16(qfB0, kf20, sB2, 0, 0, 0);
            sB2 = __builtin_amdgcn_mfma_f32_16x16x32_bf16(qfB1, kf21, sB2, 0, 0, 0);
            sB3 = __builtin_amdgcn_mfma_f32_16x16x32_bf16(qfB0, kf30, sB3, 0, 0, 0);
            sB3 = __builtin_amdgcn_mfma_f32_16x16x32_bf16(qfB1, kf31, sB3, 0, 0, 0);
        }

        // ---- V frags issued early (in flight during exp / P stores) ----
        const s16x8 vf00 = *reinterpret_cast<const s16x8*>(&vt[(r +  0) * 72 + g * 8]);
        const s16x8 vf01 = *reinterpret_cast<const s16x8*>(&vt[(r +  0) * 72 + g * 8 + 32]);
        const s16x8 vf10 = *reinterpret_cast<const s16x8*>(&vt[(r + 16) * 72 + g * 8]);
        const s16x8 vf11 = *reinterpret_cast<const s16x8*>(&vt[(r + 16) * 72 + g * 8 + 32]);
        const s16x8 vf20 = *reinterpret_cast<const s16x8*>(&vt[(r + 32) * 72 + g * 8]);
        const s16x8 vf21 = *reinterpret_cast<const s16x8*>(&vt[(r + 32) * 72 + g * 8 + 32]);
        const s16x8 vf30 = *reinterpret_cast<const s16x8*>(&vt[(r + 48) * 72 + g * 8]);
        const s16x8 vf31 = *reinterpret_cast<const s16x8*>(&vt[(r + 48) * 72 + g * 8 + 32]);

        // ---- no-max softmax ----
        #pragma unroll
        for (int j = 0; j < 4; ++j) {
            float p0 = __expf(sA0[j]);
            float p1 = __expf(sA1[j]);
            float p2 = __expf(sA2[j]);
            float p3 = __expf(sA3[j]);
            laccA[j] += (p0 + p1) + (p2 + p3);
            psw[(4 * g + j) * 72 + r +  0] = f2bf(p0);
            psw[(4 * g + j) * 72 + r + 16] = f2bf(p1);
            psw[(4 * g + j) * 72 + r + 32] = f2bf(p2);
            psw[(4 * g + j) * 72 + r + 48] = f2bf(p3);
        }
        #pragma unroll
        for (int j = 0; j < 4; ++j) {
            float p0 = __expf(sB0[j]);
            float p1 = __expf(sB1[j]);
            float p2 = __expf(sB2[j]);
            float p3 = __expf(sB3[j]);
            laccB[j] += (p0 + p1) + (p2 + p3);
            psw[(16 + 4 * g + j) * 72 + r +  0] = f2bf(p0);
            psw[(16 + 4 * g + j) * 72 + r + 16] = f2bf(p1);
            psw[(16 + 4 * g + j) * 72 + r + 32] = f2bf(p2);
            psw[(16 + 4 * g + j) * 72 + r + 48] = f2bf(p3);
        }

        // wave-local fence: P ds_writes visible to this wave's ds_reads
        asm volatile("s_waitcnt lgkmcnt(0)" ::: "memory");
        __builtin_amdgcn_sched_barrier(0);

        const s16x8 paA0 = *reinterpret_cast<const s16x8*>(&psw[r * 72 + g * 8]);
        const s16x8 paA1 = *reinterpret_cast<const s16x8*>(&psw[r * 72 + g * 8 + 32]);
        const s16x8 paB0 = *reinterpret_cast<const s16x8*>(&psw[(16 + r) * 72 + g * 8]);
        const s16x8 paB1 = *reinterpret_cast<const s16x8*>(&psw[(16 + r) * 72 + g * 8 + 32]);
        zacA0 = __builtin_amdgcn_mfma_f32_16x16x32_bf16(paA0, vf00, zacA0, 0, 0, 0);
        zacA0 = __builtin_amdgcn_mfma_f32_16x16x32_bf16(paA1, vf01, zacA0, 0, 0, 0);
        zacA1 = __builtin_amdgcn_mfma_f32_16x16x32_bf16(paA0, vf10, zacA1, 0, 0, 0);
        zacA1 = __builtin_amdgcn_mfma_f32_16x16x32_bf16(paA1, vf11, zacA1, 0, 0, 0);
        zacA2 = __builtin_amdgcn_mfma_f32_16x16x32_bf16(paA0, vf20, zacA2, 0, 0, 0);
        zacA2 = __builtin_amdgcn_mfma_f32_16x16x32_bf16(paA1, vf21, zacA2, 0, 0, 0);
        zacA3 = __builtin_amdgcn_mfma_f32_16x16x32_bf16(paA0, vf30, zacA3, 0, 0, 0);
        zacA3 = __builtin_amdgcn_mfma_f32_16x16x32_bf16(paA1, vf31, zacA3, 0, 0, 0);
        zacB0 = __builtin_amdgcn_mfma_f32_16x16x32_bf16(paB0, vf00, zacB0, 0, 0, 0);
        zacB0 = __builtin_amdgcn_mfma_f32_16x16x32_bf16(paB1, vf01, zacB0, 0, 0, 0);
        zacB1 = __builtin_amdgcn_mfma_f32_16x16x32_bf16(paB0, vf10, zacB1, 0, 0, 0);
        zacB1 = __builtin_amdgcn_mfma_f32_16x16x32_bf16(paB1, vf11, zacB1, 0, 0, 0);
        zacB2 = __builtin_amdgcn_mfma_f32_16x16x32_bf16(paB0, vf20, zacB2, 0, 0, 0);
        zacB2 = __builtin_amdgcn_mfma_f32_16x16x32_bf16(paB1, vf21, zacB2, 0, 0, 0);
        zacB3 = __builtin_amdgcn_mfma_f32_16x16x32_bf16(paB0, vf30, zacB3, 0, 0, 0);
        zacB3 = __builtin_amdgcn_mfma_f32_16x16x32_bf16(paB1, vf31, zacB3, 0, 0, 0);

        __syncthreads();               // both waves done reading ks/vt
        if (pf) {
            #pragma unroll
            for (int i = 0; i < 4; ++i) {
                const int c = t + 128 * i, key = c >> 3, sub = c & 7;
                *reinterpret_cast<s16x8*>(&ks[key * 72 + sub * 8]) = kr[i];
                *reinterpret_cast<s16x8*>(&vt[key * 72 + sub * 8]) = vr[i];
            }
        }
        __syncthreads();               // next tile staged & visible
    }

    // ---- deferred l butterfly + unnormalized partial Z ----
    const size_t rowbase = (size_t)split * BN + (size_t)bb * N_ + qrow0;
    #pragma unroll
    for (int j = 0; j < 4; ++j) {
        float lt = laccA[j];
        lt += __shfl_xor(lt, 1);
        lt += __shfl_xor(lt, 2);
        lt += __shfl_xor(lt, 4);
        lt += __shfl_xor(lt, 8);
        if (r == 0)
            lsum[rowbase + 4 * g + j] = lt;
        float* zr = Zp + (rowbase + 4 * g + j) * KD + r;
        zr[ 0] = zacA0[j];
        zr[16] = zacA1[j];
        zr[32] = zacA2[j];
        zr[48] = zacA3[j];
    }
    #pragma unroll
    for (int j = 0; j < 4; ++j) {
        float lt = laccB[j];
        lt += __shfl_xor(lt, 1);
        lt += __shfl_xor(lt, 2);
        lt += __shfl_xor(lt, 4);
        lt += __shfl_xor(lt, 8);
        if (r == 0)
            lsum[rowbase + 16 + 4 * g + j] = lt;
        float* zr = Zp + (rowbase + 16 + 4 * g + j) * KD + r;
        zr[ 0] = zacB0[j];
        zr[16] = zacB1[j];
        zr[32] = zacB2[j];
        zr[48] = zacB3[j];
    }
}

// ---------------------------------------------------------------------------
// Fused merge + 3-layer hi/lo MFMA MLP. 512 blocks x 32 rows, 256 thr.
// Wave w owns ct pair {2w,2w+1} for BOTH 16-row strips (weight frags reused).
// ---------------------------------------------------------------------------
__global__ __launch_bounds__(256)
void mlp_kernel(const float* __restrict__ Zp, const float* __restrict__ lsum,
                const unsigned short* __restrict__ pW1h, const unsigned short* __restrict__ pW1l,
                const unsigned short* __restrict__ pW2h, const unsigned short* __restrict__ pW2l,
                const unsigned short* __restrict__ pW3h, const unsigned short* __restrict__ pW3l,
                const float* __restrict__ b1, const float* __restrict__ b2,
                const float* __restrict__ b3, float* __restrict__ out) {
    __shared__ unsigned int zW[32 * 68];
    __shared__ unsigned int hW[32 * 140];
    const int t = threadIdx.x;
    const int row0 = blockIdx.x * 32;

    // ---- merge: z = (sum_s Zp_s) / (sum_s l_s); 8 cols per thread ----
    {
        const int rr = t >> 3, c8 = (t & 7) * 8;
        const size_t grow = (size_t)row0 + rr;
        const float inv = 1.0f / (lsum[grow] + lsum[BN + grow] +
                                  lsum[2 * (size_t)BN + grow] + lsum[3 * (size_t)BN + grow]);
        const size_t off = grow * KD + c8;
        uint4 wv0, wv1;
        {
            float4 a0 = *reinterpret_cast<const float4*>(Zp + off);
            float4 a1 = *reinterpret_cast<const float4*>(Zp + (size_t)BN * KD + off);
            float4 a2 = *reinterpret_cast<const float4*>(Zp + 2 * (size_t)BN * KD + off);
            float4 a3 = *reinterpret_cast<const float4*>(Zp + 3 * (size_t)BN * KD + off);
            wv0.x = packw((a0.x + a1.x + a2.x + a3.x) * inv);
            wv0.y = packw((a0.y + a1.y + a2.y + a3.y) * inv);
            wv0.z = packw((a0.z + a1.z + a2.z + a3.z) * inv);
            wv0.w = packw((a0.w + a1.w + a2.w + a3.w) * inv);
        }
        {
            float4 a0 = *reinterpret_cast<const float4*>(Zp + off + 4);
            float4 a1 = *reinterpret_cast<const float4*>(Zp + (size_t)BN * KD + off + 4);
            float4 a2 = *reinterpret_cast<const float4*>(Zp + 2 * (size_t)BN * KD + off + 4);
            float4 a3 = *reinterpret_cast<const float4*>(Zp + 3 * (size_t)BN * KD + off + 4);
            wv1.x = packw((a0.x + a1.x + a2.x + a3.x) * inv);
            wv1.y = packw((a0.y + a1.y + a2.y + a3.y) * inv);
            wv1.z = packw((a0.z + a1.z + a2.z + a3.z) * inv);
            wv1.w = packw((a0.w + a1.w + a2.w + a3.w) * inv);
        }
        *reinterpret_cast<uint4*>(&zW[rr * 68 + c8])     = wv0;
        *reinterpret_cast<uint4*>(&zW[rr * 68 + c8 + 4]) = wv1;
    }
    __syncthreads();

    const int w = t >> 6, l = t & 63, g = l >> 4, r = l & 15;
    const int ctA = 2 * w, ctB = 2 * w + 1;

    // ---- layer 1: 64 -> 128 (nch = 2), 2 strips ----
    f32x4 aA[2], aB[2];
    #pragma unroll
    for (int s = 0; s < 2; ++s) { aA[s] = (f32x4){0,0,0,0}; aB[s] = (f32x4){0,0,0,0}; }
    #pragma unroll
    for (int c = 0; c < 2; ++c) {
        s16x8 h0, l0, h1, l1;
        unpack8(&zW[r * 68 + c * 32 + g * 8], h0, l0);
        unpack8(&zW[(16 + r) * 68 + c * 32 + g * 8], h1, l1);
        const int baseA = ((ctA * 2 + c) * 64 + l) * 8;
        const int baseB = ((ctB * 2 + c) * 64 + l) * 8;
        const s16x8 bhA = *reinterpret_cast<const s16x8*>(pW1h + baseA);
        const s16x8 blA = *reinterpret_cast<const s16x8*>(pW1l + baseA);
        const s16x8 bhB = *reinterpret_cast<const s16x8*>(pW1h + baseB);
        const s16x8 blB = *reinterpret_cast<const s16x8*>(pW1l + baseB);
        aA[0] = __builtin_amdgcn_mfma_f32_16x16x32_bf16(h0, bhA, aA[0], 0, 0, 0);
        aA[0] = __builtin_amdgcn_mfma_f32_16x16x32_bf16(h0, blA, aA[0], 0, 0, 0);
        aA[0] = __builtin_amdgcn_mfma_f32_16x16x32_bf16(l0, bhA, aA[0], 0, 0, 0);
        aA[1] = __builtin_amdgcn_mfma_f32_16x16x32_bf16(h1, bhA, aA[1], 0, 0, 0);
        aA[1] = __builtin_amdgcn_mfma_f32_16x16x32_bf16(h1, blA, aA[1], 0, 0, 0);
        aA[1] = __builtin_amdgcn_mfma_f32_16x16x32_bf16(l1, bhA, aA[1], 0, 0, 0);
        aB[0] = __builtin_amdgcn_mfma_f32_16x16x32_bf16(h0, bhB, aB[0], 0, 0, 0);
        aB[0] = __builtin_amdgcn_mfma_f32_16x16x32_bf16(h0, blB, aB[0], 0, 0, 0);
        aB[0] = __builtin_amdgcn_mfma_f32_16x16x32_bf16(l0, bhB, aB[0], 0, 0, 0);
        aB[1] = __builtin_amdgcn_mfma_f32_16x16x32_bf16(h1, bhB, aB[1], 0, 0, 0);
        aB[1] = __builtin_amdgcn_mfma_f32_16x16x32_bf16(h1, blB, aB[1], 0, 0, 0);
        aB[1] = __builtin_amdgcn_mfma_f32_16x16x32_bf16(l1, bhB, aB[1], 0, 0, 0);
    }
    {
        const float bvA = b1[ctA * 16 + r], bvB = b1[ctB * 16 + r];
        #pragma unroll
        for (int s = 0; s < 2; ++s)
            #pragma unroll
            for (int reg = 0; reg < 4; ++reg) {
                const int rw = (s * 16 + 4 * g + reg) * 140;
                hW[rw + ctA * 16 + r] = packw(elu_f(aA[s][reg] + bvA));
                hW[rw + ctB * 16 + r] = packw(elu_f(aB[s][reg] + bvB));
            }
    }
    __syncthreads();

    // ---- layer 2: 128 -> 128 (nch = 4), in-place ----
    #pragma unroll
    for (int s = 0; s < 2; ++s) { aA[s] = (f32x4){0,0,0,0}; aB[s] = (f32x4){0,0,0,0}; }
    #pragma unroll
    for (int c = 0; c < 4; ++c) {
        s16x8 h0, l0, h1, l1;
        unpack8(&hW[r * 140 + c * 32 + g * 8], h0, l0);
        unpack8(&hW[(16 + r) * 140 + c * 32 + g * 8], h1, l1);
        const int baseA = ((ctA * 4 + c) * 64 + l) * 8;
        const int baseB = ((ctB * 4 + c) * 64 + l) * 8;
        const s16x8 bhA = *reinterpret_cast<const s16x8*>(pW2h + baseA);
        const s16x8 blA = *reinterpret_cast<const s16x8*>(pW2l + baseA);
        const s16x8 bhB = *reinterpret_cast<const s16x8*>(pW2h + baseB);
        const s16x8 blB = *reinterpret_cast<const s16x8*>(pW2l + baseB);
        aA[0] = __builtin_amdgcn_mfma_f32_16x16x32_bf16(h0, bhA, aA[0], 0, 0, 0);
        aA[0] = __builtin_amdgcn_mfma_f32_16x16x32_bf16(h0, blA, aA[0], 0, 0, 0);
        aA[0] = __builtin_amdgcn_mfma_f32_16x16x32_bf16(l0, bhA, aA[0], 0, 0, 0);
        aA[1] = __builtin_amdgcn_mfma_f32_16x16x32_bf16(h1, bhA, aA[1], 0, 0, 0);
        aA[1] = __builtin_amdgcn_mfma_f32_16x16x32_bf16(h1, blA, aA[1], 0, 0, 0);
        aA[1] = __builtin_amdgcn_mfma_f32_16x16x32_bf16(l1, bhA, aA[1], 0, 0, 0);
        aB[0] = __builtin_amdgcn_mfma_f32_16x16x32_bf16(h0, bhB, aB[0], 0, 0, 0);
        aB[0] = __builtin_amdgcn_mfma_f32_16x16x32_bf16(h0, blB, aB[0], 0, 0, 0);
        aB[0] = __builtin_amdgcn_mfma_f32_16x16x32_bf16(l0, bhB, aB[0], 0, 0, 0);
        aB[1] = __builtin_amdgcn_mfma_f32_16x16x32_bf16(h1, bhB, aB[1], 0, 0, 0);
        aB[1] = __builtin_amdgcn_mfma_f32_16x16x32_bf16(h1, blB, aB[1], 0, 0, 0);
        aB[1] = __builtin_amdgcn_mfma_f32_16x16x32_bf16(l1, bhB, aB[1], 0, 0, 0);
    }
    __syncthreads();   // all reads of hW done before overwrite
    {
        const float bvA = b2[ctA * 16 + r], bvB = b2[ctB * 16 + r];
        #pragma unroll
        for (int s = 0; s < 2; ++s)
            #pragma unroll
            for (int reg = 0; reg < 4; ++reg) {
                const int rw = (s * 16 + 4 * g + reg) * 140;
                hW[rw + ctA * 16 + r] = packw(elu_f(aA[s][reg] + bvA));
                hW[rw + ctB * 16 + r] = packw(elu_f(aB[s][reg] + bvB));
            }
    }
    __syncthreads();

    // ---- layer 3: 128 -> 128 -> global out ----
    #pragma unroll
    for (int s = 0; s < 2; ++s) { aA[s] = (f32x4){0,0,0,0}; aB[s] = (f32x4){0,0,0,0}; }
    #pragma unroll
    for (int c = 0; c < 4; ++c) {
        s16x8 h0, l0, h1, l1;
        unpack8(&hW[r * 140 + c * 32 + g * 8], h0, l0);
        unpack8(&hW[(16 + r) * 140 + c * 32 + g * 8], h1, l1);
        const int baseA = ((ctA * 4 + c) * 64 + l) * 8;
        const int baseB = ((ctB * 4 + c) * 64 + l) * 8;
        const s16x8 bhA = *reinterpret_cast<const s16x8*>(pW3h + baseA);
        const s16x8 blA = *reinterpret_cast<const s16x8*>(pW3l + baseA);
        const s16x8 bhB = *reinterpret_cast<const s16x8*>(pW3h + baseB);
        const s16x8 blB = *reinterpret_cast<const s16x8*>(pW3l + baseB);
        aA[0] = __builtin_amdgcn_mfma_f32_16x16x32_bf16(h0, bhA, aA[0], 0, 0, 0);
        aA[0] = __builtin_amdgcn_mfma_f32_16x16x32_bf16(h0, blA, aA[0], 0, 0, 0);
        aA[0] = __builtin_amdgcn_mfma_f32_16x16x32_bf16(l0, bhA, aA[0], 0, 0, 0);
        aA[1] = __builtin_amdgcn_mfma_f32_16x16x32_bf16(h1, bhA, aA[1], 0, 0, 0);
        aA[1] = __builtin_amdgcn_mfma_f32_16x16x32_bf16(h1, blA, aA[1], 0, 0, 0);
        aA[1] = __builtin_amdgcn_mfma_f32_16x16x32_bf16(l1, bhA, aA[1], 0, 0, 0);
        aB[0] = __builtin_amdgcn_mfma_f32_16x16x32_bf16(h0, bhB, aB[0], 0, 0, 0);
        aB[0] = __builtin_amdgcn_mfma_f32_16x16x32_bf16(h0, blB, aB[0], 0, 0, 0);
        aB[0] = __builtin_amdgcn_mfma_f32_16x16x32_bf16(l0, bhB, aB[0], 0, 0, 0);
        aB[1] = __builtin_amdgcn_mfma_f32_16x16x32_bf16(h1, bhB, aB[1], 0, 0, 0);
        aB[1] = __builtin_amdgcn_mfma_f32_16x16x32_bf16(h1, blB, aB[1], 0, 0, 0);
        aB[1] = __builtin_amdgcn_mfma_f32_16x16x32_bf16(l1, bhB, aB[1], 0, 0, 0);
    }
    {
        const float bvA = b3[ctA * 16 + r], bvB = b3[ctB * 16 + r];
        #pragma unroll
        for (int s = 0; s < 2; ++s)
            #pragma unroll
            for (int reg = 0; reg < 4; ++reg) {
                float* orow = out + (size_t)(row0 + s * 16 + 4 * g + reg) * DD;
                orow[ctA * 16 + r] = elu_f(aA[s][reg] + bvA);
                orow[ctB * 16 + r] = elu_f(aB[s][reg] + bvB);
            }
    }
}

// ---------------------------------------------------------------------------
extern "C" void kernel_launch(void* const* d_in, const int* in_sizes, int n_in,
                              void* d_out, int out_size, void* d_ws, size_t ws_size,
                              hipStream_t stream) {
    (void)in_sizes; (void)n_in; (void)out_size; (void)ws_size;
    const float* x  = (const float*)d_in[0];
    const float* Wq = (const float*)d_in[1];
    const float* Wk = (const float*)d_in[2];
    const float* Wv = (const float*)d_in[3];
    const float* W1 = (const float*)d_in[4];
    const float* b1 = (const float*)d_in[5];
    const float* W2 = (const float*)d_in[6];
    const float* b2 = (const float*)d_in[7];
    const float* W3 = (const float*)d_in[8];
    const float* b3 = (const float*)d_in[9];
    float* out = (float*)d_out;

    const size_t nt = (size_t)BN * KD;                 // 1M elements
    unsigned short* qbf = (unsigned short*)d_ws;       // bf16 [B*N][64] (prescaled)
    unsigned short* kbf = qbf + nt;                    // bf16 [B*N][64]
    unsigned short* vtb = kbf + nt;                    // bf16 [B][64][2048]
    float* Zp   = (float*)(vtb + nt);                  // f32 [KSPLIT][B*N][64]
    float* lsum = Zp + (size_t)KSPLIT * nt;            // f32 [KSPLIT][B*N]
    unsigned short* pQh  = (unsigned short*)(lsum + (size_t)KSPLIT * BN);
    unsigned short* pQl  = pQh + 49152;
    unsigned short* pW1h = pQl + 49152;
    unsigned short* pW1l = pW1h + 8192;
    unsigned short* pW2h = pW1l + 8192;
    unsigned short* pW2l = pW2h + 16384;
    unsigned short* pW3h = pW2l + 16384;
    unsigned short* pW3l = pW3h + 16384;

    pack_kernel<<<dim3(44), 256, 0, stream>>>(Wq, Wk, Wv, W1, W2, W3,
                                              pQh, pQl, pW1h, pW1l, pW2h, pW2l, pW3h, pW3l);
    qkv_kernel<<<dim3(BN / 32), 256, 0, stream>>>(x, pQh, qbf, kbf, vtb);
    attn_kernel<<<dim3(BN / 64 * KSPLIT), 128, 0, stream>>>(qbf, kbf, vtb, Zp, lsum);
    mlp_kernel<<<dim3(BN / 32), 256, 0, stream>>>(Zp, lsum, pW1h, pW1l, pW2h, pW2l,
                                                  pW3h, pW3l, b1, b2, b3, out);
}

// Round 11
// 51.913 us; speedup vs baseline: 1.0598x; 1.0598x over previous
//
#include <hip/hip_runtime.h>
#include <cstdint>
#include <cstddef>

#define B_ 8
#define N_ 2048
#define M_ 256
#define KD 64
#define DD 128
#define BN (B_ * N_)
#define KSPLIT 4
#define KT_PER (N_ / 64 / KSPLIT)   // 8 key-tiles of 64 per block

typedef __attribute__((ext_vector_type(8))) short s16x8;
typedef __attribute__((ext_vector_type(4))) float f32x4;
typedef __attribute__((ext_vector_type(4))) unsigned int u32x4;

__device__ __forceinline__ float elu_f(float x) {
    return x > 0.f ? x : (__expf(x) - 1.f);
}

// f32 -> bf16 round-to-nearest-even, raw bits
__device__ __forceinline__ unsigned short f2bf(float f) {
    unsigned int u = __float_as_uint(f);
    u = (u + 0x7FFFu + ((u >> 16) & 1u)) >> 16;
    return (unsigned short)u;
}
__device__ __forceinline__ float bf2f(unsigned short h) {
    return __uint_as_float((unsigned int)h << 16);
}
__device__ __forceinline__ unsigned short bflo(float f, unsigned short h) {
    return f2bf(f - bf2f(h));
}
// one float -> packed (hi | lo<<16) word
__device__ __forceinline__ unsigned int packw(float f) {
    unsigned short h = f2bf(f);
    unsigned short lo = bflo(f, h);
    return (unsigned int)h | ((unsigned int)lo << 16);
}
__device__ __forceinline__ unsigned int bfpack2(float a, float b) {
    return (unsigned int)f2bf(a) | ((unsigned int)f2bf(b) << 16);
}
__device__ __forceinline__ float bflo32(unsigned int u) { return __uint_as_float(u << 16); }
__device__ __forceinline__ float bfhi32(unsigned int u) { return __uint_as_float(u & 0xffff0000u); }

// unpack 8 packed (hi|lo<<16) words -> hi-frag and lo-frag
__device__ __forceinline__ void unpack8(const unsigned int* ip, s16x8& ahi, s16x8& alo) {
    const uint4 u0 = *reinterpret_cast<const uint4*>(ip);
    const uint4 u1 = *reinterpret_cast<const uint4*>(ip + 4);
    u32x4 hv, lv;
    hv.x = __byte_perm(u0.x, u0.y, 0x5410);
    hv.y = __byte_perm(u0.z, u0.w, 0x5410);
    hv.z = __byte_perm(u1.x, u1.y, 0x5410);
    hv.w = __byte_perm(u1.z, u1.w, 0x5410);
    lv.x = __byte_perm(u0.x, u0.y, 0x7632);
    lv.y = __byte_perm(u0.z, u0.w, 0x7632);
    lv.z = __byte_perm(u1.x, u1.y, 0x7632);
    lv.w = __byte_perm(u1.z, u1.w, 0x7632);
    ahi = __builtin_bit_cast(s16x8, hv);
    alo = __builtin_bit_cast(s16x8, lv);
}

// ---------------------------------------------------------------------------
// One-time weight pack (layout unchanged):
//   qkv:  base = (((mat*4+ct)*8+c)*64+lane)*8        (K=256: 8 chunks, 4 ct)
//   W1:   base = ((ct*2+c)*64+lane)*8                (K=64:  2 chunks, 8 ct)
//   W2/3: base = ((ct*4+c)*64+lane)*8                (K=128: 4 chunks, 8 ct)
// ---------------------------------------------------------------------------
__global__ __launch_bounds__(256)
void pack_kernel(const float* __restrict__ Wq, const float* __restrict__ Wk,
                 const float* __restrict__ Wv, const float* __restrict__ W1,
                 const float* __restrict__ W2, const float* __restrict__ W3,
                 unsigned short* __restrict__ pQh, unsigned short* __restrict__ pQl,
                 unsigned short* __restrict__ pW1h, unsigned short* __restrict__ pW1l,
                 unsigned short* __restrict__ pW2h, unsigned short* __restrict__ pW2l,
                 unsigned short* __restrict__ pW3h, unsigned short* __restrict__ pW3l) {
    const int id = blockIdx.x * 256 + threadIdx.x;   // 0..11263
    const float* W;
    unsigned short *ph, *pl;
    int ncol, ct, c, lane, base;
    if (id < 6144) {
        int mat = id >> 11, rem = id & 2047;
        ct = rem >> 9; c = (rem >> 6) & 7; lane = rem & 63;
        W = (mat == 0) ? Wq : (mat == 1) ? Wk : Wv;
        ncol = KD; ph = pQh; pl = pQl;
        base = (((mat * 4 + ct) * 8 + c) * 64 + lane) * 8;
    } else {
        int id2 = id - 6144;
        if (id2 < 1024) {
            ct = id2 >> 7; c = (id2 >> 6) & 1; lane = id2 & 63;
            W = W1; ncol = DD; ph = pW1h; pl = pW1l;
            base = ((ct * 2 + c) * 64 + lane) * 8;
        } else if (id2 < 3072) {
            int id3 = id2 - 1024;
            ct = id3 >> 8; c = (id3 >> 6) & 3; lane = id3 & 63;
            W = W2; ncol = DD; ph = pW2h; pl = pW2l;
            base = ((ct * 4 + c) * 64 + lane) * 8;
        } else {
            int id3 = id2 - 3072;
            ct = id3 >> 8; c = (id3 >> 6) & 3; lane = id3 & 63;
            W = W3; ncol = DD; ph = pW3h; pl = pW3l;
            base = ((ct * 4 + c) * 64 + lane) * 8;
        }
    }
    const int col = ct * 16 + (lane & 15);
    const int kb = c * 32 + (lane >> 4) * 8;
    #pragma unroll
    for (int j = 0; j < 8; ++j) {
        float v = W[(size_t)(kb + j) * ncol + col];
        unsigned short h = f2bf(v);
        ph[base + j] = h;
        pl[base + j] = bflo(v, h);
    }
}

// ---------------------------------------------------------------------------
// QKV projection, single-bf16 MFMA. 512 blocks x 32 rows, 256 thr (4 waves).
// ---------------------------------------------------------------------------
__global__ __launch_bounds__(256)
void qkv_kernel(const float* __restrict__ x,
                const unsigned short* __restrict__ pQh,
                unsigned short* __restrict__ qb, unsigned short* __restrict__ kb,
                unsigned short* __restrict__ vtb) {
    __shared__ unsigned short xh[32 * 264];
    __shared__ float dbuf[32 * 204];
    const int t = threadIdx.x;
    const int row0 = blockIdx.x * 32;

    for (int i = t; i < 2048; i += 256) {       // 32 rows x 64 float4
        int rr = i >> 6, c4 = i & 63;
        float4 v = reinterpret_cast<const float4*>(x + (size_t)(row0 + rr) * M_)[c4];
        ushort4 o;
        o.x = f2bf(v.x); o.y = f2bf(v.y); o.z = f2bf(v.z); o.w = f2bf(v.w);
        *reinterpret_cast<ushort4*>(&xh[rr * 264 + c4 * 4]) = o;
    }
    __syncthreads();

    const int w = t >> 6, l = t & 63, g = l >> 4, r = l & 15;
    const int t0 = 3 * w, t1 = 3 * w + 1, t2 = 3 * w + 2;

    f32x4 acc[3][2];
    #pragma unroll
    for (int m = 0; m < 3; ++m)
        #pragma unroll
        for (int s = 0; s < 2; ++s)
            acc[m][s] = (f32x4){0.f, 0.f, 0.f, 0.f};

    #pragma unroll
    for (int c = 0; c < 8; ++c) {
        const s16x8 a0 = *reinterpret_cast<const s16x8*>(&xh[r * 264 + c * 32 + g * 8]);
        const s16x8 a1 = *reinterpret_cast<const s16x8*>(&xh[(16 + r) * 264 + c * 32 + g * 8]);
        const s16x8 b0 = *reinterpret_cast<const s16x8*>(pQh + ((t0 * 8 + c) * 64 + l) * 8);
        const s16x8 b1 = *reinterpret_cast<const s16x8*>(pQh + ((t1 * 8 + c) * 64 + l) * 8);
        const s16x8 b2 = *reinterpret_cast<const s16x8*>(pQh + ((t2 * 8 + c) * 64 + l) * 8);
        acc[0][0] = __builtin_amdgcn_mfma_f32_16x16x32_bf16(a0, b0, acc[0][0], 0, 0, 0);
        acc[0][1] = __builtin_amdgcn_mfma_f32_16x16x32_bf16(a1, b0, acc[0][1], 0, 0, 0);
        acc[1][0] = __builtin_amdgcn_mfma_f32_16x16x32_bf16(a0, b1, acc[1][0], 0, 0, 0);
        acc[1][1] = __builtin_amdgcn_mfma_f32_16x16x32_bf16(a1, b1, acc[1][1], 0, 0, 0);
        acc[2][0] = __builtin_amdgcn_mfma_f32_16x16x32_bf16(a0, b2, acc[2][0], 0, 0, 0);
        acc[2][1] = __builtin_amdgcn_mfma_f32_16x16x32_bf16(a1, b2, acc[2][1], 0, 0, 0);
    }

    // D-frags -> dbuf: col = mat*68 + ct*16 + r, row = s*16 + 4g+reg
    {
        const int c0 = (t0 >> 2) * 68 + (t0 & 3) * 16 + r;
        const int c1 = (t1 >> 2) * 68 + (t1 & 3) * 16 + r;
        const int c2 = (t2 >> 2) * 68 + (t2 & 3) * 16 + r;
        #pragma unroll
        for (int s = 0; s < 2; ++s)
            #pragma unroll
            for (int reg = 0; reg < 4; ++reg) {
                const int rw = (s * 16 + 4 * g + reg) * 204;
                dbuf[rw + c0] = acc[0][s][reg];
                dbuf[rw + c1] = acc[1][s][reg];
                dbuf[rw + c2] = acc[2][s][reg];
            }
    }
    __syncthreads();

    const int b = row0 >> 11, n0 = row0 & 2047;
    {
        // q (mat 0, scaled 0.125) / k (mat 1): 2 mats x 32 rows x 4 quarters
        const int mat = t >> 7, rem = t & 127, rr = rem >> 2, cq = rem & 3;
        const float* src = &dbuf[rr * 204 + mat * 68 + cq * 16];
        float4 v0 = *reinterpret_cast<const float4*>(src);
        float4 v1 = *reinterpret_cast<const float4*>(src + 4);
        float4 v2 = *reinterpret_cast<const float4*>(src + 8);
        float4 v3 = *reinterpret_cast<const float4*>(src + 12);
        const float sc = (mat == 0) ? 0.125f : 1.0f;
        uint4 o0, o1;
        o0.x = bfpack2(v0.x * sc, v0.y * sc);
        o0.y = bfpack2(v0.z * sc, v0.w * sc);
        o0.z = bfpack2(v1.x * sc, v1.y * sc);
        o0.w = bfpack2(v1.z * sc, v1.w * sc);
        o1.x = bfpack2(v2.x * sc, v2.y * sc);
        o1.y = bfpack2(v2.z * sc, v2.w * sc);
        o1.z = bfpack2(v3.x * sc, v3.y * sc);
        o1.w = bfpack2(v3.z * sc, v3.w * sc);
        unsigned short* dst = (mat == 0 ? qb : kb) + (size_t)(row0 + rr) * KD + cq * 16;
        *reinterpret_cast<uint4*>(dst)     = o0;
        *reinterpret_cast<uint4*>(dst + 8) = o1;
    }
    {
        // v transposed: 64 d x 32 n -> thread: d = t>>2, 8 n
        const int d = t >> 2, ng = (t & 3) * 8;
        unsigned short tmp[8];
        #pragma unroll
        for (int i = 0; i < 8; ++i)
            tmp[i] = f2bf(dbuf[(ng + i) * 204 + 136 + d]);
        uint4 o0;
        o0.x = (unsigned)tmp[0] | ((unsigned)tmp[1] << 16);
        o0.y = (unsigned)tmp[2] | ((unsigned)tmp[3] << 16);
        o0.z = (unsigned)tmp[4] | ((unsigned)tmp[5] << 16);
        o0.w = (unsigned)tmp[6] | ((unsigned)tmp[7] << 16);
        *reinterpret_cast<uint4*>(vtb + ((size_t)b * KD + d) * N_ + n0 + ng) = o0;
    }
}

// ---------------------------------------------------------------------------
// MFMA flash attention, split-K, swapped-operand QK^T (S^T = K.Q) so each
// lane owns one q-row's scores -> softmax fully lane-local; packed P words
// ARE the PV A-frag. V staged with the key->column permutation inverse to
// the P packing: key K=8a+m lands at column
//   slot(a) + (m<4 ? m : 8+m-4),  slot(a) = 32*(a>>2) + 16*(a&1) + 4*((a>>1)&1)
// (verified bijective; inverse of kappa(8g+j) = {4g+j | 16+4g+j-4} per half).
// No P LDS, no fence. 1024 blocks x 128 thr (2 waves x 32 q-rows). Zp bf16.
// ---------------------------------------------------------------------------
__global__ __launch_bounds__(128)
void attn_kernel(const unsigned short* __restrict__ qb,
                 const unsigned short* __restrict__ kb,
                 const unsigned short* __restrict__ vtb,
                 unsigned short* __restrict__ Zp, float* __restrict__ lsum) {
    __shared__ __align__(16) unsigned short ks[64 * 72];
    __shared__ __align__(16) unsigned short vt[64 * 72];

    const int t = threadIdx.x;
    const int w = t >> 6;
    const int l = t & 63;
    const int g = l >> 4;
    const int r = l & 15;
    const int bid = blockIdx.x;
    const int split = bid & 3;
    const int qt = (bid >> 2) & 31;      // 64-row q tile
    const int bb = bid >> 7;
    const int qrow0 = qt * 64 + w * 32;  // this wave's 32 rows
    const int k0 = split * (N_ / KSPLIT);

    // Q frags (used as MFMA B-operand; layout identical to A-frag)
    const unsigned short* qrowA = qb + ((size_t)bb * N_ + qrow0 + r) * KD + g * 8;
    const unsigned short* qrowB = qrowA + (size_t)16 * KD;
    const s16x8 qfA0 = *reinterpret_cast<const s16x8*>(qrowA);
    const s16x8 qfA1 = *reinterpret_cast<const s16x8*>(qrowA + 32);
    const s16x8 qfB0 = *reinterpret_cast<const s16x8*>(qrowB);
    const s16x8 qfB1 = *reinterpret_cast<const s16x8*>(qrowB + 32);

    const unsigned short* kbase = kb + ((size_t)bb * N_ + k0) * KD;
    const unsigned short* vbase = vtb + (size_t)bb * KD * N_ + k0;

    // prologue: stage tile 0. K rows linear; V with the key permutation.
    for (int c = t; c < 512; c += 128) {
        const int row = c >> 3, sub = c & 7;
        *reinterpret_cast<s16x8*>(&ks[row * 72 + sub * 8]) =
            *reinterpret_cast<const s16x8*>(kbase + (size_t)row * KD + sub * 8);
        const s16x8 vv = *reinterpret_cast<const s16x8*>(vbase + (size_t)row * N_ + sub * 8);
        const u32x4 vw = __builtin_bit_cast(u32x4, vv);
        const int slot = 32 * (sub >> 2) + 16 * (sub & 1) + 4 * ((sub >> 1) & 1);
        *reinterpret_cast<uint2*>(&vt[row * 72 + slot])     = make_uint2(vw.x, vw.y);
        *reinterpret_cast<uint2*>(&vt[row * 72 + slot + 8]) = make_uint2(vw.z, vw.w);
    }
    __syncthreads();

    f32x4 zacA0 = {0.f,0.f,0.f,0.f}, zacA1 = {0.f,0.f,0.f,0.f};
    f32x4 zacA2 = {0.f,0.f,0.f,0.f}, zacA3 = {0.f,0.f,0.f,0.f};
    f32x4 zacB0 = {0.f,0.f,0.f,0.f}, zacB1 = {0.f,0.f,0.f,0.f};
    f32x4 zacB2 = {0.f,0.f,0.f,0.f}, zacB3 = {0.f,0.f,0.f,0.f};
    float laccA = 0.f, laccB = 0.f;

    for (int kt = 0; kt < KT_PER; ++kt) {
        // ---- prefetch next tile into regs ----
        s16x8 kr[4], vr[4];
        const bool pf = (kt + 1 < KT_PER);
        if (pf) {
            const unsigned short* kg = kbase + (size_t)(kt + 1) * 64 * KD;
            const unsigned short* vg = vbase + (size_t)(kt + 1) * 64;
            #pragma unroll
            for (int i = 0; i < 4; ++i) {
                const int c = t + 128 * i, row = c >> 3, sub = c & 7;
                kr[i] = *reinterpret_cast<const s16x8*>(kg + (size_t)row * KD + sub * 8);
                vr[i] = *reinterpret_cast<const s16x8*>(vg + (size_t)row * N_ + sub * 8);
            }
        }

        // ---- QK^T swapped: sX[t] = S^T tile t; lane (g,r): key 16t+4g+reg, q=r
        f32x4 sA[4], sB[4];
        #pragma unroll
        for (int i = 0; i < 4; ++i) { sA[i] = (f32x4){0,0,0,0}; sB[i] = (f32x4){0,0,0,0}; }
        {
            const s16x8 kf00 = *reinterpret_cast<const s16x8*>(&ks[(r +  0) * 72 + g * 8]);
            const s16x8 kf01 = *reinterpret_cast<const s16x8*>(&ks[(r +  0) * 72 + g * 8 + 32]);
            const s16x8 kf10 = *reinterpret_cast<const s16x8*>(&ks[(r + 16) * 72 + g * 8]);
            const s16x8 kf11 = *reinterpret_cast<const s16x8*>(&ks[(r + 16) * 72 + g * 8 + 32]);
            const s16x8 kf20 = *reinterpret_cast<const s16x8*>(&ks[(r + 32) * 72 + g * 8]);
            const s16x8 kf21 = *reinterpret_cast<const s16x8*>(&ks[(r + 32) * 72 + g * 8 + 32]);
            const s16x8 kf30 = *reinterpret_cast<const s16x8*>(&ks[(r + 48) * 72 + g * 8]);
            const s16x8 kf31 = *reinterpret_cast<const s16x8*>(&ks[(r + 48) * 72 + g * 8 + 32]);
            sA[0] = __builtin_amdgcn_mfma_f32_16x16x32_bf16(kf00, qfA0, sA[0], 0, 0, 0);
            sA[0] = __builtin_amdgcn_mfma_f32_16x16x32_bf16(kf01, qfA1, sA[0], 0, 0, 0);
            sA[1] = __builtin_amdgcn_mfma_f32_16x16x32_bf16(kf10, qfA0, sA[1], 0, 0, 0);
            sA[1] = __builtin_amdgcn_mfma_f32_16x16x32_bf16(kf11, qfA1, sA[1], 0, 0, 0);
            sA[2] = __builtin_amdgcn_mfma_f32_16x16x32_bf16(kf20, qfA0, sA[2], 0, 0, 0);
            sA[2] = __builtin_amdgcn_mfma_f32_16x16x32_bf16(kf21, qfA1, sA[2], 0, 0, 0);
            sA[3] = __builtin_amdgcn_mfma_f32_16x16x32_bf16(kf30, qfA0, sA[3], 0, 0, 0);
            sA[3] = __builtin_amdgcn_mfma_f32_16x16x32_bf16(kf31, qfA1, sA[3], 0, 0, 0);
            sB[0] = __builtin_amdgcn_mfma_f32_16x16x32_bf16(kf00, qfB0, sB[0], 0, 0, 0);
            sB[0] = __builtin_amdgcn_mfma_f32_16x16x32_bf16(kf01, qfB1, sB[0], 0, 0, 0);
            sB[1] = __builtin_amdgcn_mfma_f32_16x16x32_bf16(kf10, qfB0, sB[1], 0, 0, 0);
            sB[1] = __builtin_amdgcn_mfma_f32_16x16x32_bf16(kf11, qfB1, sB[1], 0, 0, 0);
            sB[2] = __builtin_amdgcn_mfma_f32_16x16x32_bf16(kf20, qfB0, sB[2], 0, 0, 0);
            sB[2] = __builtin_amdgcn_mfma_f32_16x16x32_bf16(kf21, qfB1, sB[2], 0, 0, 0);
            sB[3] = __builtin_amdgcn_mfma_f32_16x16x32_bf16(kf30, qfB0, sB[3], 0, 0, 0);
            sB[3] = __builtin_amdgcn_mfma_f32_16x16x32_bf16(kf31, qfB1, sB[3], 0, 0, 0);
        }

        // ---- lane-local no-max softmax; packed P words = PV A-frag ----
        unsigned int wA[8], wB[8];
        #pragma unroll
        for (int tt = 0; tt < 4; ++tt) {
            float p0 = __expf(sA[tt][0]);
            float p1 = __expf(sA[tt][1]);
            float p2 = __expf(sA[tt][2]);
            float p3 = __expf(sA[tt][3]);
            laccA += (p0 + p1) + (p2 + p3);
            wA[2 * tt]     = bfpack2(p0, p1);
            wA[2 * tt + 1] = bfpack2(p2, p3);
        }
        #pragma unroll
        for (int tt = 0; tt < 4; ++tt) {
            float p0 = __expf(sB[tt][0]);
            float p1 = __expf(sB[tt][1]);
            float p2 = __expf(sB[tt][2]);
            float p3 = __expf(sB[tt][3]);
            laccB += (p0 + p1) + (p2 + p3);
            wB[2 * tt]     = bfpack2(p0, p1);
            wB[2 * tt + 1] = bfpack2(p2, p3);
        }
        u32x4 pwA0 = {wA[0], wA[1], wA[2], wA[3]};
        u32x4 pwA1 = {wA[4], wA[5], wA[6], wA[7]};
        u32x4 pwB0 = {wB[0], wB[1], wB[2], wB[3]};
        u32x4 pwB1 = {wB[4], wB[5], wB[6], wB[7]};
        const s16x8 paA0 = __builtin_bit_cast(s16x8, pwA0);
        const s16x8 paA1 = __builtin_bit_cast(s16x8, pwA1);
        const s16x8 paB0 = __builtin_bit_cast(s16x8, pwB0);
        const s16x8 paB1 = __builtin_bit_cast(s16x8, pwB1);

        // ---- PV: V frags from permuted LDS; P from registers ----
        const s16x8 vf00 = *reinterpret_cast<const s16x8*>(&vt[(r +  0) * 72 + g * 8]);
        const s16x8 vf01 = *reinterpret_cast<const s16x8*>(&vt[(r +  0) * 72 + g * 8 + 32]);
        const s16x8 vf10 = *reinterpret_cast<const s16x8*>(&vt[(r + 16) * 72 + g * 8]);
        const s16x8 vf11 = *reinterpret_cast<const s16x8*>(&vt[(r + 16) * 72 + g * 8 + 32]);
        const s16x8 vf20 = *reinterpret_cast<const s16x8*>(&vt[(r + 32) * 72 + g * 8]);
        const s16x8 vf21 = *reinterpret_cast<const s16x8*>(&vt[(r + 32) * 72 + g * 8 + 32]);
        const s16x8 vf30 = *reinterpret_cast<const s16x8*>(&vt[(r + 48) * 72 + g * 8]);
        const s16x8 vf31 = *reinterpret_cast<const s16x8*>(&vt[(r + 48) * 72 + g * 8 + 32]);

        zacA0 = __builtin_amdgcn_mfma_f32_16x16x32_bf16(paA0, vf00, zacA0, 0, 0, 0);
        zacA0 = __builtin_amdgcn_mfma_f32_16x16x32_bf16(paA1, vf01, zacA0, 0, 0, 0);
        zacA1 = __builtin_amdgcn_mfma_f32_16x16x32_bf16(paA0, vf10, zacA1, 0, 0, 0);
        zacA1 = __builtin_amdgcn_mfma_f32_16x16x32_bf16(paA1, vf11, zacA1, 0, 0, 0);
        zacA2 = __builtin_amdgcn_mfma_f32_16x16x32_bf16(paA0, vf20, zacA2, 0, 0, 0);
        zacA2 = __builtin_amdgcn_mfma_f32_16x16x32_bf16(paA1, vf21, zacA2, 0, 0, 0);
        zacA3 = __builtin_amdgcn_mfma_f32_16x16x32_bf16(paA0, vf30, zacA3, 0, 0, 0);
        zacA3 = __builtin_amdgcn_mfma_f32_16x16x32_bf16(paA1, vf31, zacA3, 0, 0, 0);
        zacB0 = __builtin_amdgcn_mfma_f32_16x16x32_bf16(paB0, vf00, zacB0, 0, 0, 0);
        zacB0 = __builtin_amdgcn_mfma_f32_16x16x32_bf16(paB1, vf01, zacB0, 0, 0, 0);
        zacB1 = __builtin_amdgcn_mfma_f32_16x16x32_bf16(paB0, vf10, zacB1, 0, 0, 0);
        zacB1 = __builtin_amdgcn_mfma_f32_16x16x32_bf16(paB1, vf11, zacB1, 0, 0, 0);
        zacB2 = __builtin_amdgcn_mfma_f32_16x16x32_bf16(paB0, vf20, zacB2, 0, 0, 0);
        zacB2 = __builtin_amdgcn_mfma_f32_16x16x32_bf16(paB1, vf21, zacB2, 0, 0, 0);
        zacB3 = __builtin_amdgcn_mfma_f32_16x16x32_bf16(paB0, vf30, zacB3, 0, 0, 0);
        zacB3 = __builtin_amdgcn_mfma_f32_16x16x32_bf16(paB1, vf31, zacB3, 0, 0, 0);

        __syncthreads();               // both waves done reading ks/vt
        if (pf) {
            #pragma unroll
            for (int i = 0; i < 4; ++i) {
                const int c = t + 128 * i, row = c >> 3, sub = c & 7;
                *reinterpret_cast<s16x8*>(&ks[row * 72 + sub * 8]) = kr[i];
                const u32x4 vw = __builtin_bit_cast(u32x4, vr[i]);
                const int slot = 32 * (sub >> 2) + 16 * (sub & 1) + 4 * ((sub >> 1) & 1);
                *reinterpret_cast<uint2*>(&vt[row * 72 + slot])     = make_uint2(vw.x, vw.y);
                *reinterpret_cast<uint2*>(&vt[row * 72 + slot + 8]) = make_uint2(vw.z, vw.w);
            }
        }
        __syncthreads();               // next tile staged & visible
    }

    // ---- deferred l reduction (4 g-lanes per q-row) + bf16 partial Z ----
    const size_t rowbase = (size_t)split * BN + (size_t)bb * N_ + qrow0;
    {
        float ltA = laccA;
        ltA += __shfl_xor(ltA, 16);
        ltA += __shfl_xor(ltA, 32);
        float ltB = laccB;
        ltB += __shfl_xor(ltB, 16);
        ltB += __shfl_xor(ltB, 32);
        if (l < 16) {
            lsum[rowbase + r]      = ltA;
            lsum[rowbase + 16 + r] = ltB;
        }
    }
    #pragma unroll
    for (int reg = 0; reg < 4; ++reg) {
        unsigned short* zrA = Zp + (rowbase + 4 * g + reg) * KD + r;
        zrA[ 0] = f2bf(zacA0[reg]);
        zrA[16] = f2bf(zacA1[reg]);
        zrA[32] = f2bf(zacA2[reg]);
        zrA[48] = f2bf(zacA3[reg]);
        unsigned short* zrB = Zp + (rowbase + 16 + 4 * g + reg) * KD + r;
        zrB[ 0] = f2bf(zacB0[reg]);
        zrB[16] = f2bf(zacB1[reg]);
        zrB[32] = f2bf(zacB2[reg]);
        zrB[48] = f2bf(zacB3[reg]);
    }
}

// ---------------------------------------------------------------------------
// Fused merge + 3-layer hi/lo MFMA MLP. 512 blocks x 32 rows, 256 thr.
// Merge reads bf16 partial Z.
// ---------------------------------------------------------------------------
__global__ __launch_bounds__(256)
void mlp_kernel(const unsigned short* __restrict__ Zp, const float* __restrict__ lsum,
                const unsigned short* __restrict__ pW1h, const unsigned short* __restrict__ pW1l,
                const unsigned short* __restrict__ pW2h, const unsigned short* __restrict__ pW2l,
                const unsigned short* __restrict__ pW3h, const unsigned short* __restrict__ pW3l,
                const float* __restrict__ b1, const float* __restrict__ b2,
                const float* __restrict__ b3, float* __restrict__ out) {
    __shared__ unsigned int zW[32 * 68];
    __shared__ unsigned int hW[32 * 140];
    const int t = threadIdx.x;
    const int row0 = blockIdx.x * 32;

    // ---- merge: z = (sum_s Zp_s) / (sum_s l_s); 8 cols per thread ----
    {
        const int rr = t >> 3, c8 = (t & 7) * 8;
        const size_t grow = (size_t)row0 + rr;
        const float inv = 1.0f / (lsum[grow] + lsum[BN + grow] +
                                  lsum[2 * (size_t)BN + grow] + lsum[3 * (size_t)BN + grow]);
        const size_t off = grow * KD + c8;
        const uint4 z0 = *reinterpret_cast<const uint4*>(Zp + off);
        const uint4 z1 = *reinterpret_cast<const uint4*>(Zp + (size_t)BN * KD + off);
        const uint4 z2 = *reinterpret_cast<const uint4*>(Zp + 2 * (size_t)BN * KD + off);
        const uint4 z3 = *reinterpret_cast<const uint4*>(Zp + 3 * (size_t)BN * KD + off);
        const unsigned int a0[4] = {z0.x, z0.y, z0.z, z0.w};
        const unsigned int a1[4] = {z1.x, z1.y, z1.z, z1.w};
        const unsigned int a2[4] = {z2.x, z2.y, z2.z, z2.w};
        const unsigned int a3[4] = {z3.x, z3.y, z3.z, z3.w};
        unsigned int ww[8];
        #pragma unroll
        for (int i = 0; i < 4; ++i) {
            float lo = bflo32(a0[i]) + bflo32(a1[i]) + bflo32(a2[i]) + bflo32(a3[i]);
            float hi = bfhi32(a0[i]) + bfhi32(a1[i]) + bfhi32(a2[i]) + bfhi32(a3[i]);
            ww[2 * i]     = packw(lo * inv);
            ww[2 * i + 1] = packw(hi * inv);
        }
        uint4 o0, o1;
        o0.x = ww[0]; o0.y = ww[1]; o0.z = ww[2]; o0.w = ww[3];
        o1.x = ww[4]; o1.y = ww[5]; o1.z = ww[6]; o1.w = ww[7];
        *reinterpret_cast<uint4*>(&zW[rr * 68 + c8])     = o0;
        *reinterpret_cast<uint4*>(&zW[rr * 68 + c8 + 4]) = o1;
    }
    __syncthreads();

    const int w = t >> 6, l = t & 63, g = l >> 4, r = l & 15;
    const int ctA = 2 * w, ctB = 2 * w + 1;

    // ---- layer 1: 64 -> 128 (nch = 2), 2 strips ----
    f32x4 aA[2], aB[2];
    #pragma unroll
    for (int s = 0; s < 2; ++s) { aA[s] = (f32x4){0,0,0,0}; aB[s] = (f32x4){0,0,0,0}; }
    #pragma unroll
    for (int c = 0; c < 2; ++c) {
        s16x8 h0, l0, h1, l1;
        unpack8(&zW[r * 68 + c * 32 + g * 8], h0, l0);
        unpack8(&zW[(16 + r) * 68 + c * 32 + g * 8], h1, l1);
        const int baseA = ((ctA * 2 + c) * 64 + l) * 8;
        const int baseB = ((ctB * 2 + c) * 64 + l) * 8;
        const s16x8 bhA = *reinterpret_cast<const s16x8*>(pW1h + baseA);
        const s16x8 blA = *reinterpret_cast<const s16x8*>(pW1l + baseA);
        const s16x8 bhB = *reinterpret_cast<const s16x8*>(pW1h + baseB);
        const s16x8 blB = *reinterpret_cast<const s16x8*>(pW1l + baseB);
        aA[0] = __builtin_amdgcn_mfma_f32_16x16x32_bf16(h0, bhA, aA[0], 0, 0, 0);
        aA[0] = __builtin_amdgcn_mfma_f32_16x16x32_bf16(h0, blA, aA[0], 0, 0, 0);
        aA[0] = __builtin_amdgcn_mfma_f32_16x16x32_bf16(l0, bhA, aA[0], 0, 0, 0);
        aA[1] = __builtin_amdgcn_mfma_f32_16x16x32_bf16(h1, bhA, aA[1], 0, 0, 0);
        aA[1] = __builtin_amdgcn_mfma_f32_16x16x32_bf16(h1, blA, aA[1], 0, 0, 0);
        aA[1] = __builtin_amdgcn_mfma_f32_16x16x32_bf16(l1, bhA, aA[1], 0, 0, 0);
        aB[0] = __builtin_amdgcn_mfma_f32_16x16x32_bf16(h0, bhB, aB[0], 0, 0, 0);
        aB[0] = __builtin_amdgcn_mfma_f32_16x16x32_bf16(h0, blB, aB[0], 0, 0, 0);
        aB[0] = __builtin_amdgcn_mfma_f32_16x16x32_bf16(l0, bhB, aB[0], 0, 0, 0);
        aB[1] = __builtin_amdgcn_mfma_f32_16x16x32_bf16(h1, bhB, aB[1], 0, 0, 0);
        aB[1] = __builtin_amdgcn_mfma_f32_16x16x32_bf16(h1, blB, aB[1], 0, 0, 0);
        aB[1] = __builtin_amdgcn_mfma_f32_16x16x32_bf16(l1, bhB, aB[1], 0, 0, 0);
    }
    {
        const float bvA = b1[ctA * 16 + r], bvB = b1[ctB * 16 + r];
        #pragma unroll
        for (int s = 0; s < 2; ++s)
            #pragma unroll
            for (int reg = 0; reg < 4; ++reg) {
                const int rw = (s * 16 + 4 * g + reg) * 140;
                hW[rw + ctA * 16 + r] = packw(elu_f(aA[s][reg] + bvA));
                hW[rw + ctB * 16 + r] = packw(elu_f(aB[s][reg] + bvB));
            }
    }
    __syncthreads();

    // ---- layer 2: 128 -> 128 (nch = 4), in-place ----
    #pragma unroll
    for (int s = 0; s < 2; ++s) { aA[s] = (f32x4){0,0,0,0}; aB[s] = (f32x4){0,0,0,0}; }
    #pragma unroll
    for (int c = 0; c < 4; ++c) {
        s16x8 h0, l0, h1, l1;
        unpack8(&hW[r * 140 + c * 32 + g * 8], h0, l0);
        unpack8(&hW[(16 + r) * 140 + c * 32 + g * 8], h1, l1);
        const int baseA = ((ctA * 4 + c) * 64 + l) * 8;
        const int baseB = ((ctB * 4 + c) * 64 + l) * 8;
        const s16x8 bhA = *reinterpret_cast<const s16x8*>(pW2h + baseA);
        const s16x8 blA = *reinterpret_cast<const s16x8*>(pW2l + baseA);
        const s16x8 bhB = *reinterpret_cast<const s16x8*>(pW2h + baseB);
        const s16x8 blB = *reinterpret_cast<const s16x8*>(pW2l + baseB);
        aA[0] = __builtin_amdgcn_mfma_f32_16x16x32_bf16(h0, bhA, aA[0], 0, 0, 0);
        aA[0] = __builtin_amdgcn_mfma_f32_16x16x32_bf16(h0, blA, aA[0], 0, 0, 0);
        aA[0] = __builtin_amdgcn_mfma_f32_16x16x32_bf16(l0, bhA, aA[0], 0, 0, 0);
        aA[1] = __builtin_amdgcn_mfma_f32_16x16x32_bf16(h1, bhA, aA[1], 0, 0, 0);
        aA[1] = __builtin_amdgcn_mfma_f32_16x16x32_bf16(h1, blA, aA[1], 0, 0, 0);
        aA[1] = __builtin_amdgcn_mfma_f32_16x16x32_bf16(l1, bhA, aA[1], 0, 0, 0);
        aB[0] = __builtin_amdgcn_mfma_f32_16x16x32_bf16(h0, bhB, aB[0], 0, 0, 0);
        aB[0] = __builtin_amdgcn_mfma_f32_16x16x32_bf16(h0, blB, aB[0], 0, 0, 0);
        aB[0] = __builtin_amdgcn_mfma_f32_16x16x32_bf16(l0, bhB, aB[0], 0, 0, 0);
        aB[1] = __builtin_amdgcn_mfma_f32_16x16x32_bf16(h1, bhB, aB[1], 0, 0, 0);
        aB[1] = __builtin_amdgcn_mfma_f32_16x16x32_bf16(h1, blB, aB[1], 0, 0, 0);
        aB[1] = __builtin_amdgcn_mfma_f32_16x16x32_bf16(l1, bhB, aB[1], 0, 0, 0);
    }
    __syncthreads();   // all reads of hW done before overwrite
    {
        const float bvA = b2[ctA * 16 + r], bvB = b2[ctB * 16 + r];
        #pragma unroll
        for (int s = 0; s < 2; ++s)
            #pragma unroll
            for (int reg = 0; reg < 4; ++reg) {
                const int rw = (s * 16 + 4 * g + reg) * 140;
                hW[rw + ctA * 16 + r] = packw(elu_f(aA[s][reg] + bvA));
                hW[rw + ctB * 16 + r] = packw(elu_f(aB[s][reg] + bvB));
            }
    }
    __syncthreads();

    // ---- layer 3: 128 -> 128 -> global out ----
    #pragma unroll
    for (int s = 0; s < 2; ++s) { aA[s] = (f32x4){0,0,0,0}; aB[s] = (f32x4){0,0,0,0}; }
    #pragma unroll
    for (int c = 0; c < 4; ++c) {
        s16x8 h0, l0, h1, l1;
        unpack8(&hW[r * 140 + c * 32 + g * 8], h0, l0);
        unpack8(&hW[(16 + r) * 140 + c * 32 + g * 8], h1, l1);
        const int baseA = ((ctA * 4 + c) * 64 + l) * 8;
        const int baseB = ((ctB * 4 + c) * 64 + l) * 8;
        const s16x8 bhA = *reinterpret_cast<const s16x8*>(pW3h + baseA);
        const s16x8 blA = *reinterpret_cast<const s16x8*>(pW3l + baseA);
        const s16x8 bhB = *reinterpret_cast<const s16x8*>(pW3h + baseB);
        const s16x8 blB = *reinterpret_cast<const s16x8*>(pW3l + baseB);
        aA[0] = __builtin_amdgcn_mfma_f32_16x16x32_bf16(h0, bhA, aA[0], 0, 0, 0);
        aA[0] = __builtin_amdgcn_mfma_f32_16x16x32_bf16(h0, blA, aA[0], 0, 0, 0);
        aA[0] = __builtin_amdgcn_mfma_f32_16x16x32_bf16(l0, bhA, aA[0], 0, 0, 0);
        aA[1] = __builtin_amdgcn_mfma_f32_16x16x32_bf16(h1, bhA, aA[1], 0, 0, 0);
        aA[1] = __builtin_amdgcn_mfma_f32_16x16x32_bf16(h1, blA, aA[1], 0, 0, 0);
        aA[1] = __builtin_amdgcn_mfma_f32_16x16x32_bf16(l1, bhA, aA[1], 0, 0, 0);
        aB[0] = __builtin_amdgcn_mfma_f32_16x16x32_bf16(h0, bhB, aB[0], 0, 0, 0);
        aB[0] = __builtin_amdgcn_mfma_f32_16x16x32_bf16(h0, blB, aB[0], 0, 0, 0);
        aB[0] = __builtin_amdgcn_mfma_f32_16x16x32_bf16(l0, bhB, aB[0], 0, 0, 0);
        aB[1] = __builtin_amdgcn_mfma_f32_16x16x32_bf16(h1, bhB, aB[1], 0, 0, 0);
        aB[1] = __builtin_amdgcn_mfma_f32_16x16x32_bf16(h1, blB, aB[1], 0, 0, 0);
        aB[1] = __builtin_amdgcn_mfma_f32_16x16x32_bf16(l1, bhB, aB[1], 0, 0, 0);
    }
    {
        const float bvA = b3[ctA * 16 + r], bvB = b3[ctB * 16 + r];
        #pragma unroll
        for (int s = 0; s < 2; ++s)
            #pragma unroll
            for (int reg = 0; reg < 4; ++reg) {
                float* orow = out + (size_t)(row0 + s * 16 + 4 * g + reg) * DD;
                orow[ctA * 16 + r] = elu_f(aA[s][reg] + bvA);
                orow[ctB * 16 + r] = elu_f(aB[s][reg] + bvB);
            }
    }
}

// ---------------------------------------------------------------------------
extern "C" void kernel_launch(void* const* d_in, const int* in_sizes, int n_in,
                              void* d_out, int out_size, void* d_ws, size_t ws_size,
                              hipStream_t stream) {
    (void)in_sizes; (void)n_in; (void)out_size; (void)ws_size;
    const float* x  = (const float*)d_in[0];
    const float* Wq = (const float*)d_in[1];
    const float* Wk = (const float*)d_in[2];
    const float* Wv = (const float*)d_in[3];
    const float* W1 = (const float*)d_in[4];
    const float* b1 = (const float*)d_in[5];
    const float* W2 = (const float*)d_in[6];
    const float* b2 = (const float*)d_in[7];
    const float* W3 = (const float*)d_in[8];
    const float* b3 = (const float*)d_in[9];
    float* out = (float*)d_out;

    const size_t nt = (size_t)BN * KD;                 // 1M elements
    unsigned short* qbf = (unsigned short*)d_ws;       // bf16 [B*N][64] (prescaled)
    unsigned short* kbf = qbf + nt;                    // bf16 [B*N][64]
    unsigned short* vtb = kbf + nt;                    // bf16 [B][64][2048]
    unsigned short* Zp  = vtb + nt;                    // bf16 [KSPLIT][B*N][64]
    float* lsum = (float*)(Zp + (size_t)KSPLIT * nt);  // f32 [KSPLIT][B*N]
    unsigned short* pQh  = (unsigned short*)(lsum + (size_t)KSPLIT * BN);
    unsigned short* pQl  = pQh + 49152;
    unsigned short* pW1h = pQl + 49152;
    unsigned short* pW1l = pW1h + 8192;
    unsigned short* pW2h = pW1l + 8192;
    unsigned short* pW2l = pW2h + 16384;
    unsigned short* pW3h = pW2l + 16384;
    unsigned short* pW3l = pW3h + 16384;

    pack_kernel<<<dim3(44), 256, 0, stream>>>(Wq, Wk, Wv, W1, W2, W3,
                                              pQh, pQl, pW1h, pW1l, pW2h, pW2l, pW3h, pW3l);
    qkv_kernel<<<dim3(BN / 32), 256, 0, stream>>>(x, pQh, qbf, kbf, vtb);
    attn_kernel<<<dim3(BN / 64 * KSPLIT), 128, 0, stream>>>(qbf, kbf, vtb, Zp, lsum);
    mlp_kernel<<<dim3(BN / 32), 256, 0, stream>>>(Zp, lsum, pW1h, pW1l, pW2h, pW2l,
                                                  pW3h, pW3l, b1, b2, b3, out);
}